// Round 2
// baseline (13911.209 us; speedup 1.0000x reference)
//
#include <hip/hip_runtime.h>
#include <math.h>

// CustomGRU B=64,S=512,F=512,H=1024. FP32 I/O, split-bf16 (hi+lo) MFMA compute.
// Round 7: h broadcast was uncached-LLC-bound (64MB/step grid, no cache dedup,
// ~10us of the 14.5us step). Changes:
//  (1) h loads now PLAIN CACHEABLE (L1+L2) + per-step agent-acquire fence
//      (__builtin_amdgcn_fence -> buffer_inv) so each XCD cold-fills h once
//      from LLC and L2 serves the 32x broadcast (8MB/XCD/step @ ~4.3TB/s).
//  (2) ALL result stores uncached sc0 sc1 (buffer_inv would drop dirty L2
//      lines) -> also kills the write-allocate amplification (WRITE_SIZE was
//      2.3GB for 256MB of data).
//  (3) Epilogue: one wave (tid<64), 4 cols per thread; h state kept in
//      REGISTERS (hf array deleted); stores packed: dwordx4 out + 2x dwordx2
//      h hi/lo = 192 store transactions/WG/step vs 1024 scattered 2-4B.
//  Kept: distributed 8-line barrier, single-round-trip poll, x-GEMM for t+1
//  in the post-arrive shadow.

#define B_   64
#define S_   512
#define F_   512
#define H_   1024
#define KTOT 1536
#define NG   4096
#define NWG  256
#define NTHR 512
#define RS   1544             // padded LDS row stride (shorts)
#define CPS  324              // Cp tile stride (floats)
#define SMEM_BYTES (2 * 16 * RS * 2 + 32 * CPS * 4)   // 98816 + 41472 = 140288

typedef short short8 __attribute__((ext_vector_type(8)));
typedef float floatx4 __attribute__((ext_vector_type(4)));
typedef unsigned int uint2v __attribute__((ext_vector_type(2)));

__device__ __forceinline__ float bf2f(unsigned short u) {
    union { unsigned int i; float f; } v; v.i = ((unsigned int)u) << 16; return v.f;
}
__device__ __forceinline__ unsigned short f2bf(float f) {
    union { float f; unsigned int i; } v; v.f = f;
    unsigned int x = v.i;
    x += 0x7fffu + ((x >> 16) & 1u);
    return (unsigned short)(x >> 16);
}
__device__ __forceinline__ void split2(float v, unsigned short& hi, unsigned short& lo) {
    hi = f2bf(v);
    lo = f2bf(v - bf2f(hi));
}
__device__ __forceinline__ float tanh_fast(float a) {
    float e = __expf(-2.f * fabsf(a));      // in (0,1], no overflow
    float t = (1.f - e) / (1.f + e);
    return copysignf(t, a);
}

__global__ void pack_w(const float* __restrict__ Wih,
                       const float* __restrict__ Whh,
                       unsigned short* __restrict__ Whi,
                       unsigned short* __restrict__ Wlo) {
    int idx = blockIdx.x * 256 + threadIdx.x;   // < NG*KTOT
    int p = idx / KTOT;
    int k = idx - p * KTOT;
    int j = p >> 2, g = p & 3;
    float v = 0.f;
    if (g == 0)      v = (k < F_) ? Wih[k * 3072 + j]        : Whh[(k - F_) * 3072 + j];
    else if (g == 1) v = (k < F_) ? Wih[k * 3072 + 1024 + j] : Whh[(k - F_) * 3072 + 1024 + j];
    else if (g == 2) { if (k <  F_) v = Wih[k * 3072 + 2048 + j]; }
    else             { if (k >= F_) v = Whh[(k - F_) * 3072 + 2048 + j]; }
    unsigned short hi, lo; split2(v, hi, lo);
    Whi[idx] = hi; Wlo[idx] = lo;
}

__global__ void pack_x(const float* __restrict__ x,
                       unsigned short* __restrict__ xhi,
                       unsigned short* __restrict__ xlo) {
    int idx = blockIdx.x * 256 + threadIdx.x;   // < B_*S_*F_
    unsigned short hi, lo; split2(x[idx], hi, lo);
    xhi[idx] = hi; xlo[idx] = lo;
}

// x-side K step: plain cacheable (L1/L2) hi/lo loads
__device__ __forceinline__ void ks_step_x(floatx4* acc,
    const unsigned short* __restrict__ Ahi, const unsigned short* __restrict__ Alo,
    size_t aofs, const unsigned short* Bh_, const unsigned short* Bl_, int bofs)
{
    short8 bh = *(const short8*)&Bh_[bofs];
    short8 bl = *(const short8*)&Bl_[bofs];
    #pragma unroll
    for (int mt = 0; mt < 4; ++mt) {
        size_t o = aofs + (size_t)mt * ((size_t)16 * S_ * F_);
        short8 ah = *(const short8*)&Ahi[o];
        short8 al = *(const short8*)&Alo[o];
        acc[mt] = __builtin_amdgcn_mfma_f32_16x16x32_bf16(ah, bh, acc[mt], 0, 0, 0);
        acc[mt] = __builtin_amdgcn_mfma_f32_16x16x32_bf16(ah, bl, acc[mt], 0, 0, 0);
        acc[mt] = __builtin_amdgcn_mfma_f32_16x16x32_bf16(al, bh, acc[mt], 0, 0, 0);
    }
}

// h-side K step: plain cacheable loads (L2 serves the 32x per-XCD broadcast;
// freshness guaranteed by the per-step agent-acquire fence).
__device__ __forceinline__ void ks_step_h_c(floatx4* acc,
    const unsigned short* Hhi, const unsigned short* Hlo, size_t aofs,
    const unsigned short* Bh_, const unsigned short* Bl_, int bofs)
{
    short8 bh = *(const short8*)&Bh_[bofs];
    short8 bl = *(const short8*)&Bl_[bofs];
    #pragma unroll
    for (int mt = 0; mt < 4; ++mt) {
        size_t o = aofs + (size_t)mt * ((size_t)16 * H_);
        short8 ah = *(const short8*)&Hhi[o];
        short8 al = *(const short8*)&Hlo[o];
        acc[mt] = __builtin_amdgcn_mfma_f32_16x16x32_bf16(ah, bh, acc[mt], 0, 0, 0);
        acc[mt] = __builtin_amdgcn_mfma_f32_16x16x32_bf16(ah, bl, acc[mt], 0, 0, 0);
        acc[mt] = __builtin_amdgcn_mfma_f32_16x16x32_bf16(al, bh, acc[mt], 0, 0, 0);
    }
}

__global__ __launch_bounds__(NTHR, 2) void gru_persist(
    const unsigned short* __restrict__ xhi,
    const unsigned short* __restrict__ xlo,
    const unsigned short* __restrict__ Whi,
    const unsigned short* __restrict__ Wlo,
    const float* __restrict__ bias,
    unsigned short* hhi0, unsigned short* hlo0,
    unsigned short* hhi1, unsigned short* hlo1,
    float* __restrict__ out,
    float* __restrict__ hlast,
    unsigned* bar)
{
    extern __shared__ char smem[];
    unsigned short* Bh = (unsigned short*)smem;                 // 16 x RS shorts
    unsigned short* Bl = Bh + 16 * RS;
    float* Cp = (float*)(smem + 2 * 16 * RS * 2);               // 32 tiles x CPS f32

    const int tid = threadIdx.x;
    const int wg  = blockIdx.x;

    // ---- stage this wg's weight slice into LDS (once) ----
    for (int c = tid; c < 16 * 192; c += NTHR) {
        int row = c / 192, c8 = c - row * 192;
        size_t gofs = (size_t)(wg * 16 + row) * KTOT + c8 * 8;
        *(short8*)&Bh[row * RS + c8 * 8] = *(const short8*)&Whi[gofs];
        *(short8*)&Bl[row * RS + c8 * 8] = *(const short8*)&Wlo[gofs];
    }
    __syncthreads();

    const int lane = tid & 63;
    const int kw   = tid >> 6;                 // wave id 0..7
    const int l15  = lane & 15, quad = lane >> 4;
    // uniform split: wave kw covers x-K [kw*64, +64) and h-K [kw*128, +128)
    const int xk0   = kw * 64;
    const int hk0   = kw * 128;
    const int bofsx = l15 * RS + xk0 + quad * 8;
    const int bofsh = l15 * RS + 512 + hk0 + quad * 8;

    // epilogue: ONE wave; thread eb=tid (<64) owns batch row eb, cols wg*4..+3
    floatx4 bZ4 = {0,0,0,0}, bR4 = {0,0,0,0}, bE4 = {0,0,0,0};
    if (tid < 64) {
        bZ4 = *(const floatx4*)&bias[wg * 4];
        bR4 = *(const floatx4*)&bias[H_ + wg * 4];
        bE4 = *(const floatx4*)&bias[2 * H_ + wg * 4];
    }
    const int emt  = (tid >> 4) & 3, erow = tid & 15;
    const int cbase = 80 * (erow >> 2) + (erow & 3);
    const int hbidx = tid * H_ + wg * 4;       // h/hlast store base (tid<64)

    const size_t hrow = (size_t)l15 * H_ + quad * 8;
    const int cpw = lane * 4 + (lane >> 2) * 4;   // padded Cp write offset

    float hcur[4] = {0.f, 0.f, 0.f, 0.f};      // persistent h state in regs

    floatx4 z4v = {0.f, 0.f, 0.f, 0.f};

    // prologue: x-side contribution for t=0
    floatx4 accx[4] = {z4v, z4v, z4v, z4v};
    {
        const size_t xrow0 = ((size_t)l15 * S_) * F_ + quad * 8;
        #pragma unroll
        for (int ks = 0; ks < 2; ++ks)
            ks_step_x(accx, xhi, xlo, xrow0 + xk0 + ks * 32, Bh, Bl, bofsx + ks * 32);
    }

    for (int t = 0; t < S_; ++t) {
        const unsigned short* hih = (t & 1) ? hhi1 : hhi0;
        const unsigned short* hil = (t & 1) ? hlo1 : hlo0;
        unsigned short* hoh = (t & 1) ? hhi0 : hhi1;
        unsigned short* hol = (t & 1) ? hlo0 : hlo1;

        // make prior step's h stores (at LLC) visible: invalidate L1+L2
        __builtin_amdgcn_fence(__ATOMIC_ACQUIRE, "agent");

        floatx4 acc[4] = {accx[0], accx[1], accx[2], accx[3]};
        #pragma unroll
        for (int ks = 0; ks < 4; ++ks)
            ks_step_h_c(acc, hih, hil, hrow + hk0 + ks * 32, Bh, Bl, bofsh + ks * 32);

        #pragma unroll
        for (int mt = 0; mt < 4; ++mt)
            *(floatx4*)&Cp[(kw * 4 + mt) * CPS + cpw] = acc[mt];
        __syncthreads();

        if (tid < 64) {
            float hn[4]; unsigned short his[4], los[4];
            #pragma unroll
            for (int j = 0; j < 4; ++j) {
                float s[4];
                #pragma unroll
                for (int gi = 0; gi < 4; ++gi) {
                    // c = 4j+gi; coff = cbase + 4c + 4*(c>>2)
                    const int coff = cbase + 20 * j + 4 * gi;
                    float a = 0.f;
                    #pragma unroll
                    for (int k2 = 0; k2 < 8; ++k2)
                        a += Cp[(k2 * 4 + emt) * CPS + coff];
                    s[gi] = a;
                }
                float z   = 1.f / (1.f + __expf(-(s[0] + bZ4[j])));
                float rr  = 1.f / (1.f + __expf(-(s[1] + bR4[j])));
                float eta = tanh_fast(s[2] + bE4[j] + rr * tanh_fast(s[3]));
                float v   = z * hcur[j] + (1.f - z) * eta;
                hcur[j] = v; hn[j] = v;
                split2(v, his[j], los[j]);
            }
            uint2v hp = { (unsigned)his[0] | ((unsigned)his[1] << 16),
                          (unsigned)his[2] | ((unsigned)his[3] << 16) };
            uint2v lp = { (unsigned)los[0] | ((unsigned)los[1] << 16),
                          (unsigned)los[2] | ((unsigned)los[3] << 16) };
            floatx4 ov = { hn[0], hn[1], hn[2], hn[3] };
            asm volatile("global_store_dwordx2 %0, %1, off sc0 sc1"
                         :: "v"(&hoh[hbidx]), "v"(hp) : "memory");
            asm volatile("global_store_dwordx2 %0, %1, off sc0 sc1"
                         :: "v"(&hol[hbidx]), "v"(lp) : "memory");
            asm volatile("global_store_dwordx4 %0, %1, off sc0 sc1"
                         :: "v"(&out[((size_t)tid * S_ + t) * H_ + wg * 4]), "v"(ov)
                         : "memory");
            if (t == S_ - 1)
                asm volatile("global_store_dwordx4 %0, %1, off sc0 sc1"
                             :: "v"(&hlast[hbidx]), "v"(ov) : "memory");
        }
        // drain h (and out) stores to LLC, then arrive
        asm volatile("s_waitcnt vmcnt(0)" ::: "memory");
        __syncthreads();
        if (tid == 0)
            __hip_atomic_fetch_add(&bar[(wg & 7) * 32], 1u,
                                   __ATOMIC_RELAXED, __HIP_MEMORY_SCOPE_AGENT);

        // x-side GEMM for t+1 overlaps with barrier propagation
        if (t + 1 < S_) {
            #pragma unroll
            for (int mt = 0; mt < 4; ++mt) accx[mt] = z4v;
            const size_t xrow = ((size_t)l15 * S_ + (t + 1)) * F_ + quad * 8;
            #pragma unroll
            for (int ks = 0; ks < 2; ++ks)
                ks_step_x(accx, xhi, xlo, xrow + xk0 + ks * 32, Bh, Bl, bofsx + ks * 32);
        }

        // distributed-counter poll: 8 lines, one round trip per poll
        if (tid == 0) {
            const unsigned target = (unsigned)(t + 1) * NWG;
            for (;;) {
                unsigned c0, c1, c2, c3, c4, c5, c6, c7;
                asm volatile(
                    "global_load_dword %0, %[a0], off sc0 sc1\n\t"
                    "global_load_dword %1, %[a1], off sc0 sc1\n\t"
                    "global_load_dword %2, %[a2], off sc0 sc1\n\t"
                    "global_load_dword %3, %[a3], off sc0 sc1\n\t"
                    "global_load_dword %4, %[a4], off sc0 sc1\n\t"
                    "global_load_dword %5, %[a5], off sc0 sc1\n\t"
                    "global_load_dword %6, %[a6], off sc0 sc1\n\t"
                    "global_load_dword %7, %[a7], off sc0 sc1\n\t"
                    "s_waitcnt vmcnt(0)"
                    : "=&v"(c0), "=&v"(c1), "=&v"(c2), "=&v"(c3),
                      "=&v"(c4), "=&v"(c5), "=&v"(c6), "=&v"(c7)
                    : [a0]"v"(bar),       [a1]"v"(bar + 32),
                      [a2]"v"(bar + 64),  [a3]"v"(bar + 96),
                      [a4]"v"(bar + 128), [a5]"v"(bar + 160),
                      [a6]"v"(bar + 192), [a7]"v"(bar + 224)
                    : "memory");
                if (c0 + c1 + c2 + c3 + c4 + c5 + c6 + c7 >= target) break;
                __builtin_amdgcn_s_sleep(1);
            }
        }
        __syncthreads();
    }
}

extern "C" void kernel_launch(void* const* d_in, const int* in_sizes, int n_in,
                              void* d_out, int out_size, void* d_ws, size_t ws_size,
                              hipStream_t stream) {
    const float* x    = (const float*)d_in[0];   // [B,S,F]
    const float* Wih  = (const float*)d_in[1];   // [F,3H]
    const float* Whh  = (const float*)d_in[2];   // [H,3H]
    const float* bias = (const float*)d_in[3];   // [3H]
    float* out = (float*)d_out;                  // [B,S,H] ++ [B,H]

    char* ws = (char*)d_ws;
    unsigned short* Whi = (unsigned short*)ws; ws += (size_t)NG * KTOT * 2;
    unsigned short* Wlo = (unsigned short*)ws; ws += (size_t)NG * KTOT * 2;
    unsigned short* xhi = (unsigned short*)ws; ws += (size_t)B_ * S_ * F_ * 2;
    unsigned short* xlo = (unsigned short*)ws; ws += (size_t)B_ * S_ * F_ * 2;
    unsigned short* hhi0 = (unsigned short*)ws; ws += (size_t)B_ * H_ * 2;
    unsigned short* hlo0 = (unsigned short*)ws; ws += (size_t)B_ * H_ * 2;
    unsigned short* hhi1 = (unsigned short*)ws; ws += (size_t)B_ * H_ * 2;
    unsigned short* hlo1 = (unsigned short*)ws; ws += (size_t)B_ * H_ * 2;
    unsigned* bar = (unsigned*)ws;             ws += 1024;

    hipMemsetAsync(hhi0, 0, (size_t)B_ * H_ * 2, stream);
    hipMemsetAsync(hlo0, 0, (size_t)B_ * H_ * 2, stream);
    hipMemsetAsync(bar,  0, 1024, stream);

    pack_w<<<(NG * KTOT) / 256, 256, 0, stream>>>(Wih, Whh, Whi, Wlo);
    pack_x<<<(B_ * S_ * F_) / 256, 256, 0, stream>>>(x, xhi, xlo);

    float* hlast = out + (size_t)B_ * S_ * H_;
    void* args[] = { &xhi, &xlo, &Whi, &Wlo, &bias,
                     &hhi0, &hlo0, &hhi1, &hlo1, &out, &hlast, &bar };
    hipLaunchCooperativeKernel((void*)gru_persist, dim3(NWG), dim3(NTHR),
                               args, SMEM_BYTES, stream);
}

// Round 5
// 7076.083 us; speedup vs baseline: 1.9659x; 1.9659x over previous
//
#include <hip/hip_runtime.h>
#include <math.h>

// CustomGRU B=64,S=512,F=512,H=1024. FP32 I/O, split-bf16 (hi+lo) MFMA compute.
// Round 10: r9 with the Cp-stride bug fixed.
//  Post-mortem: r8 requested 165888 B LDS (CPS=324) > 163840 max -> launch
//  failure. r9 shrank CPS to 260 but kept the r8 padded write pattern whose
//  max offset is 315 -> Cp tile rows overlapped by 56 floats -> absmax 1.6.
//  Fix: revert to r6's proven UNPADDED Cp layout (cpw = lane*4, max 255 < 260;
//  epilogue positions 64*quad + 16*(lc&3) + 4g + reg). LDS stays 133120 B
//  (launch-proven in r5/r6). ~4-way epilogue bank conflict accepted for now.
// Design (r8/r9): 64 WGs x 64 p-cols. h-broadcast (uncached LLC) 16MB/step
// (was 64 at NWG=256), barrier 64 arrivals. Weights tile-packed, streamed from
// L2 (3.1MB/XCD resident), fragment loads 64 lanes x 16B coalesced. h stored
// fragment-major so uncached A-loads are 1KB-contiguous via offset:. h-phase
// depth-2 asm pipeline, counted vmcnt(8/8/8/0) (+sched_barrier). Packed
// dword/dwordx2 uncached stores (kills write-allocate amplification).
// x-GEMM for t+1 in the post-arrive barrier shadow.

#define B_   64
#define S_   512
#define F_   512
#define H_   1024
#define KTOT 1536
#define NG   4096
#define NWG  64
#define NTHR 512
#define CPS  260              // Cp tile stride (floats); 128 tiles
#define SMEM_BYTES (128 * CPS * 4)   // 133120

typedef short short8 __attribute__((ext_vector_type(8)));
typedef float floatx4 __attribute__((ext_vector_type(4)));
typedef float floatx2 __attribute__((ext_vector_type(2)));

__device__ __forceinline__ float bf2f(unsigned short u) {
    union { unsigned int i; float f; } v; v.i = ((unsigned int)u) << 16; return v.f;
}
__device__ __forceinline__ unsigned short f2bf(float f) {
    union { float f; unsigned int i; } v; v.f = f;
    unsigned int x = v.i;
    x += 0x7fffu + ((x >> 16) & 1u);
    return (unsigned short)(x >> 16);
}
__device__ __forceinline__ void split2(float v, unsigned short& hi, unsigned short& lo) {
    hi = f2bf(v);
    lo = f2bf(v - bf2f(hi));
}
__device__ __forceinline__ float tanh_fast(float a) {
    float e = __expf(-2.f * fabsf(a));
    float t = (1.f - e) / (1.f + e);
    return copysignf(t, a);
}

// Tile-packed weights: idx = (((wg*48 + kc)*4 + ct)*64 + lane)*8 + e
// (wg: 64 p-cols; kc: 32-K chunk 0..47 [0..15 x-side, 16..47 h-side];
//  ct: 16-col tile; lane = quad*16+l15 -> p = wg*64+ct*16+l15, k = kc*32+quad*8+e)
__global__ void pack_w2(const float* __restrict__ Wih,
                        const float* __restrict__ Whh,
                        unsigned short* __restrict__ Whi,
                        unsigned short* __restrict__ Wlo) {
    int idx = blockIdx.x * 256 + threadIdx.x;   // < 6291456
    int e    = idx & 7;
    int lane = (idx >> 3) & 63;
    int ct   = (idx >> 9) & 3;
    int tmp  = idx >> 11;
    int kc   = tmp % 48;
    int wgi  = tmp / 48;
    int l15 = lane & 15, quad = lane >> 4;
    int p = wgi * 64 + ct * 16 + l15;
    int k = kc * 32 + quad * 8 + e;
    int j = p >> 2, g = p & 3;
    float v = 0.f;
    if (k < F_) {
        if (g == 0)      v = Wih[k * 3072 + j];
        else if (g == 1) v = Wih[k * 3072 + 1024 + j];
        else if (g == 2) v = Wih[k * 3072 + 2048 + j];
    } else {
        int hk = k - F_;
        if (g == 0)      v = Whh[hk * 3072 + j];
        else if (g == 1) v = Whh[hk * 3072 + 1024 + j];
        else if (g == 3) v = Whh[hk * 3072 + 2048 + j];
    }
    unsigned short hi, lo; split2(v, hi, lo);
    Whi[idx] = hi; Wlo[idx] = lo;
}

__global__ void pack_x(const float* __restrict__ x,
                       unsigned short* __restrict__ xhi,
                       unsigned short* __restrict__ xlo) {
    int idx = blockIdx.x * 256 + threadIdx.x;   // < B_*S_*F_
    unsigned short hi, lo; split2(x[idx], hi, lo);
    xhi[idx] = hi; xlo[idx] = lo;
}

// D = A*B + C over all 16 (mt,ct) tiles: A[0..3]=ah, A[4..7]=al; B likewise.
__device__ __forceinline__ void mfma_block(floatx4* acc, const short8* A, const short8* Bv) {
    #pragma unroll
    for (int ct = 0; ct < 4; ++ct)
        #pragma unroll
        for (int mt = 0; mt < 4; ++mt) {
            floatx4 a = acc[mt * 4 + ct];
            a = __builtin_amdgcn_mfma_f32_16x16x32_bf16(A[mt],     Bv[ct],     a, 0, 0, 0);
            a = __builtin_amdgcn_mfma_f32_16x16x32_bf16(A[mt],     Bv[4 + ct], a, 0, 0, 0);
            a = __builtin_amdgcn_mfma_f32_16x16x32_bf16(A[4 + mt], Bv[ct],     a, 0, 0, 0);
            acc[mt * 4 + ct] = a;
        }
}

// x-side GEMM (2 K-steps), all cacheable plain loads; compiler schedules.
__device__ __forceinline__ void x_gemm(floatx4* acc,
    const unsigned short* __restrict__ xhi, const unsigned short* __restrict__ xlo,
    const unsigned short* __restrict__ wxh, const unsigned short* __restrict__ wxl,
    size_t xbase)
{
    #pragma unroll
    for (int ks = 0; ks < 2; ++ks) {
        short8 A[8], Bv[8];
        #pragma unroll
        for (int mt = 0; mt < 4; ++mt) {
            size_t o = xbase + (size_t)mt * (16 * S_ * F_) + ks * 32;
            A[mt]     = *(const short8*)&xhi[o];
            A[4 + mt] = *(const short8*)&xlo[o];
        }
        #pragma unroll
        for (int ct = 0; ct < 4; ++ct) {
            Bv[ct]     = *(const short8*)&wxh[ks * 2048 + ct * 512];
            Bv[4 + ct] = *(const short8*)&wxl[ks * 2048 + ct * 512];
        }
        mfma_block(acc, A, Bv);
    }
}

// 8 uncached h-A loads (4 mt x hi/lo) in two 4-output asm blocks.
#define LOADH2(A, PH, PL) do { \
    asm volatile( \
        "global_load_dwordx4 %0, %[h], off sc0 sc1\n\t" \
        "global_load_dwordx4 %1, %[h], off offset:1024 sc0 sc1\n\t" \
        "global_load_dwordx4 %2, %[h], off offset:2048 sc0 sc1\n\t" \
        "global_load_dwordx4 %3, %[h], off offset:3072 sc0 sc1" \
        : "=&v"(A[0]), "=&v"(A[1]), "=&v"(A[2]), "=&v"(A[3]) \
        : [h]"v"(PH) : "memory"); \
    asm volatile( \
        "global_load_dwordx4 %0, %[l], off sc0 sc1\n\t" \
        "global_load_dwordx4 %1, %[l], off offset:1024 sc0 sc1\n\t" \
        "global_load_dwordx4 %2, %[l], off offset:2048 sc0 sc1\n\t" \
        "global_load_dwordx4 %3, %[l], off offset:3072 sc0 sc1" \
        : "=&v"(A[4]), "=&v"(A[5]), "=&v"(A[6]), "=&v"(A[7]) \
        : [l]"v"(PL) : "memory"); \
    } while (0)

// 8 cacheable weight-B loads (4 ct x hi/lo) - asm so they count in MY vmcnt.
#define LOADW2(Bv, PH, PL) do { \
    asm volatile( \
        "global_load_dwordx4 %0, %[h], off\n\t" \
        "global_load_dwordx4 %1, %[h], off offset:1024\n\t" \
        "global_load_dwordx4 %2, %[h], off offset:2048\n\t" \
        "global_load_dwordx4 %3, %[h], off offset:3072" \
        : "=&v"(Bv[0]), "=&v"(Bv[1]), "=&v"(Bv[2]), "=&v"(Bv[3]) \
        : [h]"v"(PH) : "memory"); \
    asm volatile( \
        "global_load_dwordx4 %0, %[l], off\n\t" \
        "global_load_dwordx4 %1, %[l], off offset:1024\n\t" \
        "global_load_dwordx4 %2, %[l], off offset:2048\n\t" \
        "global_load_dwordx4 %3, %[l], off offset:3072" \
        : "=&v"(Bv[4]), "=&v"(Bv[5]), "=&v"(Bv[6]), "=&v"(Bv[7]) \
        : [l]"v"(PL) : "memory"); \
    } while (0)

#define WAITVM(N) do { \
        asm volatile("s_waitcnt vmcnt(" #N ")" ::: "memory"); \
        __builtin_amdgcn_sched_barrier(0); \
    } while (0)

__global__ __launch_bounds__(NTHR, 1) void gru_persist(
    const unsigned short* __restrict__ xhi,
    const unsigned short* __restrict__ xlo,
    const unsigned short* __restrict__ Whi,
    const unsigned short* __restrict__ Wlo,
    const float* __restrict__ bias,
    unsigned short* hhi0, unsigned short* hlo0,
    unsigned short* hhi1, unsigned short* hlo1,
    float* __restrict__ out,
    float* __restrict__ hlast,
    unsigned* bar)
{
    extern __shared__ char smem[];
    float* Cp = (float*)smem;                   // 128 tiles x CPS f32

    const int tid = threadIdx.x;
    const int wg  = blockIdx.x;

    const int lane = tid & 63;
    const int kw   = tid >> 6;                  // wave 0..7 = K-split
    const int l15  = lane & 15, quad = lane >> 4;
    const int cpw  = lane * 4;                  // UNPADDED (max 255 < CPS=260)

    // weight roots (tile-packed, cacheable): x-side kc = kw*2+ks, h-side kc = 16+kw*4+ks
    const unsigned short* wxh = Whi + ((size_t)(wg * 48 + kw * 2) * 4) * 512 + lane * 8;
    const unsigned short* wxl = Wlo + ((size_t)(wg * 48 + kw * 2) * 4) * 512 + lane * 8;
    const unsigned short* whh = Whi + ((size_t)(wg * 48 + 16 + kw * 4) * 4) * 512 + lane * 8;
    const unsigned short* whl = Wlo + ((size_t)(wg * 48 + 16 + kw * 4) * 4) * 512 + lane * 8;

    // epilogue: thread -> (batch b, 2 cols)
    const int b   = tid >> 3, j2 = tid & 7, lc0 = 2 * j2;
    const int mt_e = b >> 4, rt = b & 15;
    const int tb0  = 64 * (rt >> 2) + (rt & 3);   // unpadded: 64*quad + reg
    const int c0   = wg * 16 + lc0;
    float bZ[2], bR[2], bE[2];
    bZ[0] = bias[c0];            bZ[1] = bias[c0 + 1];
    bR[0] = bias[H_ + c0];       bR[1] = bias[H_ + c0 + 1];
    bE[0] = bias[2 * H_ + c0];   bE[1] = bias[2 * H_ + c0 + 1];
    // h store idx (fragment-major): (c>>5)*2048 + mt*512 + ((c>>3)&3)*128 + rt*8 + (c&7)
    const int hidx = (((c0 >> 5) * 4 + mt_e) * 4 + ((c0 >> 3) & 3)) * 128 + rt * 8 + (c0 & 7);

    float hcur0 = 0.f, hcur1 = 0.f;             // persistent h state in regs

    floatx4 acc[16];
    #pragma unroll
    for (int i = 0; i < 16; ++i) acc[i] = (floatx4){0.f, 0.f, 0.f, 0.f};

    // prologue: x-side contribution for t=0
    x_gemm(acc, xhi, xlo, wxh, wxl,
           ((size_t)l15 * S_ + 0) * F_ + kw * 64 + quad * 8);

    #pragma unroll 1
    for (int t = 0; t < S_; ++t) {
        const unsigned short* hih = (t & 1) ? hhi1 : hhi0;
        const unsigned short* hil = (t & 1) ? hlo1 : hlo0;
        unsigned short* hoh = (t & 1) ? hhi0 : hhi1;
        unsigned short* hol = (t & 1) ? hlo0 : hlo1;

        // ---- h-phase: depth-2 pipeline, counted vmcnt ----
        // (vmcnt==0 at entry: preceding __syncthreads drained all vmem)
        const unsigned short* hb = hih + (size_t)kw * 8192 + lane * 8;
        const unsigned short* lb = hil + (size_t)kw * 8192 + lane * 8;
        short8 A0[8], A1[8], Bv[8];

        LOADH2(A0, hb, lb);                                   // ks0 A
        LOADW2(Bv, whh, whl);                                 // ks0 B
        LOADH2(A1, hb + 2048, lb + 2048);                     // ks1 A
        WAITVM(8);  mfma_block(acc, A0, Bv);                  // ks0
        LOADW2(Bv, whh + 2048, whl + 2048);                   // ks1 B
        LOADH2(A0, hb + 4096, lb + 4096);                     // ks2 A
        WAITVM(8);  mfma_block(acc, A1, Bv);                  // ks1
        LOADW2(Bv, whh + 4096, whl + 4096);                   // ks2 B
        LOADH2(A1, hb + 6144, lb + 6144);                     // ks3 A
        WAITVM(8);  mfma_block(acc, A0, Bv);                  // ks2
        LOADW2(Bv, whh + 6144, whl + 6144);                   // ks3 B
        WAITVM(0);  mfma_block(acc, A1, Bv);                  // ks3

        // ---- LDS reduction scratch ----
        #pragma unroll
        for (int mt = 0; mt < 4; ++mt)
            #pragma unroll
            for (int ct = 0; ct < 4; ++ct)
                *(floatx4*)&Cp[((kw * 4 + mt) * 4 + ct) * CPS + cpw] = acc[mt * 4 + ct];
        __syncthreads();

        // ---- epilogue: all 512 threads, 2 cols each ----
        {
            float hn0, hn1;
            unsigned short his0, his1, los0, los1;
            #pragma unroll
            for (int u = 0; u < 2; ++u) {
                const int lc = lc0 + u;
                const int ct = lc >> 2;
                const int off0 = tb0 + 16 * (lc & 3);   // unpadded: +4g per gate
                float s0 = 0.f, s1 = 0.f, s2 = 0.f, s3 = 0.f;
                #pragma unroll
                for (int k2 = 0; k2 < 8; ++k2) {
                    const int tb = ((k2 * 4 + mt_e) * 4 + ct) * CPS + off0;
                    s0 += Cp[tb];      s1 += Cp[tb + 4];
                    s2 += Cp[tb + 8];  s3 += Cp[tb + 12];
                }
                float z   = 1.f / (1.f + __expf(-(s0 + bZ[u])));
                float rr  = 1.f / (1.f + __expf(-(s1 + bR[u])));
                float eta = tanh_fast(s2 + bE[u] + rr * tanh_fast(s3));
                float hc  = u ? hcur1 : hcur0;
                float v   = z * hc + (1.f - z) * eta;
                if (u) { hcur1 = v; hn1 = v; split2(v, his1, los1); }
                else   { hcur0 = v; hn0 = v; split2(v, his0, los0); }
            }
            unsigned hp = (unsigned)his0 | ((unsigned)his1 << 16);
            unsigned lp = (unsigned)los0 | ((unsigned)los1 << 16);
            floatx2 ov = { hn0, hn1 };
            asm volatile("global_store_dword %0, %1, off sc0 sc1"
                         :: "v"(&hoh[hidx]), "v"(hp) : "memory");
            asm volatile("global_store_dword %0, %1, off sc0 sc1"
                         :: "v"(&hol[hidx]), "v"(lp) : "memory");
            asm volatile("global_store_dwordx2 %0, %1, off sc0 sc1"
                         :: "v"(&out[((size_t)b * S_ + t) * H_ + c0]), "v"(ov)
                         : "memory");
            if (t == S_ - 1)
                asm volatile("global_store_dwordx2 %0, %1, off sc0 sc1"
                             :: "v"(&hlast[b * H_ + c0]), "v"(ov) : "memory");
        }

        if (t + 1 < S_) {
            // drain stores, then arrive
            asm volatile("s_waitcnt vmcnt(0)" ::: "memory");
            __syncthreads();
            if (tid == 0)
                __hip_atomic_fetch_add(&bar[(wg & 7) * 32], 1u,
                                       __ATOMIC_RELAXED, __HIP_MEMORY_SCOPE_AGENT);

            // x-side GEMM for t+1 in the barrier shadow (acc reused, zeroed)
            #pragma unroll
            for (int i = 0; i < 16; ++i) acc[i] = (floatx4){0.f, 0.f, 0.f, 0.f};
            x_gemm(acc, xhi, xlo, wxh, wxl,
                   ((size_t)l15 * S_ + (t + 1)) * F_ + kw * 64 + quad * 8);

            // distributed-counter poll: 8 lines, one round trip per poll
            if (tid == 0) {
                const unsigned target = (unsigned)(t + 1) * NWG;
                for (;;) {
                    unsigned cc0, cc1, cc2, cc3, cc4, cc5, cc6, cc7;
                    asm volatile(
                        "global_load_dword %0, %[a0], off sc0 sc1\n\t"
                        "global_load_dword %1, %[a1], off sc0 sc1\n\t"
                        "global_load_dword %2, %[a2], off sc0 sc1\n\t"
                        "global_load_dword %3, %[a3], off sc0 sc1\n\t"
                        "global_load_dword %4, %[a4], off sc0 sc1\n\t"
                        "global_load_dword %5, %[a5], off sc0 sc1\n\t"
                        "global_load_dword %6, %[a6], off sc0 sc1\n\t"
                        "global_load_dword %7, %[a7], off sc0 sc1\n\t"
                        "s_waitcnt vmcnt(0)"
                        : "=&v"(cc0), "=&v"(cc1), "=&v"(cc2), "=&v"(cc3),
                          "=&v"(cc4), "=&v"(cc5), "=&v"(cc6), "=&v"(cc7)
                        : [a0]"v"(bar),       [a1]"v"(bar + 32),
                          [a2]"v"(bar + 64),  [a3]"v"(bar + 96),
                          [a4]"v"(bar + 128), [a5]"v"(bar + 160),
                          [a6]"v"(bar + 192), [a7]"v"(bar + 224)
                        : "memory");
                    if (cc0 + cc1 + cc2 + cc3 + cc4 + cc5 + cc6 + cc7 >= target) break;
                    __builtin_amdgcn_s_sleep(1);
                }
            }
            __syncthreads();
        }
    }
}

extern "C" void kernel_launch(void* const* d_in, const int* in_sizes, int n_in,
                              void* d_out, int out_size, void* d_ws, size_t ws_size,
                              hipStream_t stream) {
    const float* x    = (const float*)d_in[0];   // [B,S,F]
    const float* Wih  = (const float*)d_in[1];   // [F,3H]
    const float* Whh  = (const float*)d_in[2];   // [H,3H]
    const float* bias = (const float*)d_in[3];   // [3H]
    float* out = (float*)d_out;                  // [B,S,H] ++ [B,H]

    char* ws = (char*)d_ws;
    unsigned short* Whi = (unsigned short*)ws; ws += (size_t)NG * KTOT * 2;
    unsigned short* Wlo = (unsigned short*)ws; ws += (size_t)NG * KTOT * 2;
    unsigned short* xhi = (unsigned short*)ws; ws += (size_t)B_ * S_ * F_ * 2;
    unsigned short* xlo = (unsigned short*)ws; ws += (size_t)B_ * S_ * F_ * 2;
    unsigned short* hhi0 = (unsigned short*)ws; ws += (size_t)B_ * H_ * 2;
    unsigned short* hlo0 = (unsigned short*)ws; ws += (size_t)B_ * H_ * 2;
    unsigned short* hhi1 = (unsigned short*)ws; ws += (size_t)B_ * H_ * 2;
    unsigned short* hlo1 = (unsigned short*)ws; ws += (size_t)B_ * H_ * 2;
    unsigned* bar = (unsigned*)ws;             ws += 1024;

    hipMemsetAsync(hhi0, 0, (size_t)B_ * H_ * 2, stream);
    hipMemsetAsync(hlo0, 0, (size_t)B_ * H_ * 2, stream);
    hipMemsetAsync(bar,  0, 1024, stream);

    pack_w2<<<(NG * KTOT) / 256, 256, 0, stream>>>(Wih, Whh, Whi, Wlo);
    pack_x<<<(B_ * S_ * F_) / 256, 256, 0, stream>>>(x, xhi, xlo);

    float* hlast = out + (size_t)B_ * S_ * H_;
    void* args[] = { &xhi, &xlo, &Whi, &Wlo, &bias,
                     &hhi0, &hlo0, &hhi1, &hlo1, &out, &hlast, &bar };
    hipLaunchCooperativeKernel((void*)gru_persist, dim3(NWG), dim3(NTHR),
                               args, SMEM_BYTES, stream);
}

// Round 7
// 6494.306 us; speedup vs baseline: 2.1421x; 1.0896x over previous
//
#include <hip/hip_runtime.h>
#include <math.h>

// CustomGRU B=64,S=512,F=512,H=1024. FP32 I/O, split-bf16 (hi+lo) MFMA compute.
// Round 12: r10 (proven 7076us) + the two SAFE r11 changes only.
//  Post-mortem r11 (hang, container died twice): prime suspect = s_sleep
//  removed from poll (64 WGs spinning uncached loads on the same 8 LLC lines
//  the arrivals RMW -> starvation/livelock; r6/r10 with s_sleep never hung).
//  B0-resident retimed ladder also reverted (bundled risk).
//  Kept from r11:
//  (1) Pass-reordered mfma_block: 3 sweeps over 16 independent tiles (dep
//      distance 16) instead of 3 chained MFMAs/tile (dep distance 1).
//      Theory: per-active-CU MfmaUtil 29% >> pure-issue ~9% -> dep stalls.
//  (2) out/hlast stores AFTER the arrive: pre-arrive vmcnt(0) drains only the
//      2 h-dwords. Ladder robustness: WAITVM(N) leaves outstanding exactly
//      the N newest loads (mine); stale older stores are forced complete ->
//      cannot corrupt the counted ladder.
// Everything else identical to r10: NWG=64 x 512thr, tile-packed L2-resident
// weights, fragment-major uncached h exchange, depth-2 vmcnt(8/8/8/0) ladder,
// unpadded Cp (CPS=260, 133120B LDS), 8-line barrier + s_sleep(1) poll,
// x-GEMM for t+1 in the post-arrive shadow.

#define B_   64
#define S_   512
#define F_   512
#define H_   1024
#define KTOT 1536
#define NG   4096
#define NWG  64
#define NTHR 512
#define CPS  260              // Cp tile stride (floats); 128 tiles
#define SMEM_BYTES (128 * CPS * 4)   // 133120

typedef short short8 __attribute__((ext_vector_type(8)));
typedef float floatx4 __attribute__((ext_vector_type(4)));
typedef float floatx2 __attribute__((ext_vector_type(2)));

__device__ __forceinline__ float bf2f(unsigned short u) {
    union { unsigned int i; float f; } v; v.i = ((unsigned int)u) << 16; return v.f;
}
__device__ __forceinline__ unsigned short f2bf(float f) {
    union { float f; unsigned int i; } v; v.f = f;
    unsigned int x = v.i;
    x += 0x7fffu + ((x >> 16) & 1u);
    return (unsigned short)(x >> 16);
}
__device__ __forceinline__ void split2(float v, unsigned short& hi, unsigned short& lo) {
    hi = f2bf(v);
    lo = f2bf(v - bf2f(hi));
}
__device__ __forceinline__ float tanh_fast(float a) {
    float e = __expf(-2.f * fabsf(a));
    float t = (1.f - e) / (1.f + e);
    return copysignf(t, a);
}

// Tile-packed weights: idx = (((wg*48 + kc)*4 + ct)*64 + lane)*8 + e
__global__ void pack_w2(const float* __restrict__ Wih,
                        const float* __restrict__ Whh,
                        unsigned short* __restrict__ Whi,
                        unsigned short* __restrict__ Wlo) {
    int idx = blockIdx.x * 256 + threadIdx.x;   // < 6291456
    int e    = idx & 7;
    int lane = (idx >> 3) & 63;
    int ct   = (idx >> 9) & 3;
    int tmp  = idx >> 11;
    int kc   = tmp % 48;
    int wgi  = tmp / 48;
    int l15 = lane & 15, quad = lane >> 4;
    int p = wgi * 64 + ct * 16 + l15;
    int k = kc * 32 + quad * 8 + e;
    int j = p >> 2, g = p & 3;
    float v = 0.f;
    if (k < F_) {
        if (g == 0)      v = Wih[k * 3072 + j];
        else if (g == 1) v = Wih[k * 3072 + 1024 + j];
        else if (g == 2) v = Wih[k * 3072 + 2048 + j];
    } else {
        int hk = k - F_;
        if (g == 0)      v = Whh[hk * 3072 + j];
        else if (g == 1) v = Whh[hk * 3072 + 1024 + j];
        else if (g == 3) v = Whh[hk * 3072 + 2048 + j];
    }
    unsigned short hi, lo; split2(v, hi, lo);
    Whi[idx] = hi; Wlo[idx] = lo;
}

__global__ void pack_x(const float* __restrict__ x,
                       unsigned short* __restrict__ xhi,
                       unsigned short* __restrict__ xlo) {
    int idx = blockIdx.x * 256 + threadIdx.x;   // < B_*S_*F_
    unsigned short hi, lo; split2(x[idx], hi, lo);
    xhi[idx] = hi; xlo[idx] = lo;
}

// Pass-reordered: 3 sweeps of 16 independent tiles -> dep distance 16 MFMAs.
__device__ __forceinline__ void mfma_block(floatx4* acc, const short8* A, const short8* Bv) {
    #pragma unroll
    for (int mt = 0; mt < 4; ++mt)
        #pragma unroll
        for (int ct = 0; ct < 4; ++ct)
            acc[mt * 4 + ct] = __builtin_amdgcn_mfma_f32_16x16x32_bf16(
                A[mt], Bv[ct], acc[mt * 4 + ct], 0, 0, 0);
    #pragma unroll
    for (int mt = 0; mt < 4; ++mt)
        #pragma unroll
        for (int ct = 0; ct < 4; ++ct)
            acc[mt * 4 + ct] = __builtin_amdgcn_mfma_f32_16x16x32_bf16(
                A[mt], Bv[4 + ct], acc[mt * 4 + ct], 0, 0, 0);
    #pragma unroll
    for (int mt = 0; mt < 4; ++mt)
        #pragma unroll
        for (int ct = 0; ct < 4; ++ct)
            acc[mt * 4 + ct] = __builtin_amdgcn_mfma_f32_16x16x32_bf16(
                A[4 + mt], Bv[ct], acc[mt * 4 + ct], 0, 0, 0);
}

// x-side GEMM (2 K-steps), all cacheable plain loads; compiler schedules.
__device__ __forceinline__ void x_gemm(floatx4* acc,
    const unsigned short* __restrict__ xhi, const unsigned short* __restrict__ xlo,
    const unsigned short* __restrict__ wxh, const unsigned short* __restrict__ wxl,
    size_t xbase)
{
    #pragma unroll
    for (int ks = 0; ks < 2; ++ks) {
        short8 A[8], Bv[8];
        #pragma unroll
        for (int mt = 0; mt < 4; ++mt) {
            size_t o = xbase + (size_t)mt * (16 * S_ * F_) + ks * 32;
            A[mt]     = *(const short8*)&xhi[o];
            A[4 + mt] = *(const short8*)&xlo[o];
        }
        #pragma unroll
        for (int ct = 0; ct < 4; ++ct) {
            Bv[ct]     = *(const short8*)&wxh[ks * 2048 + ct * 512];
            Bv[4 + ct] = *(const short8*)&wxl[ks * 2048 + ct * 512];
        }
        mfma_block(acc, A, Bv);
    }
}

// 8 uncached h-A loads (4 mt x hi/lo) in two 4-output asm blocks.
#define LOADH2(A, PH, PL) do { \
    asm volatile( \
        "global_load_dwordx4 %0, %[h], off sc0 sc1\n\t" \
        "global_load_dwordx4 %1, %[h], off offset:1024 sc0 sc1\n\t" \
        "global_load_dwordx4 %2, %[h], off offset:2048 sc0 sc1\n\t" \
        "global_load_dwordx4 %3, %[h], off offset:3072 sc0 sc1" \
        : "=&v"(A[0]), "=&v"(A[1]), "=&v"(A[2]), "=&v"(A[3]) \
        : [h]"v"(PH) : "memory"); \
    asm volatile( \
        "global_load_dwordx4 %0, %[l], off sc0 sc1\n\t" \
        "global_load_dwordx4 %1, %[l], off offset:1024 sc0 sc1\n\t" \
        "global_load_dwordx4 %2, %[l], off offset:2048 sc0 sc1\n\t" \
        "global_load_dwordx4 %3, %[l], off offset:3072 sc0 sc1" \
        : "=&v"(A[4]), "=&v"(A[5]), "=&v"(A[6]), "=&v"(A[7]) \
        : [l]"v"(PL) : "memory"); \
    } while (0)

// 8 cacheable weight-B loads (4 ct x hi/lo) - asm so they count in MY vmcnt.
#define LOADW2(Bv, PH, PL) do { \
    asm volatile( \
        "global_load_dwordx4 %0, %[h], off\n\t" \
        "global_load_dwordx4 %1, %[h], off offset:1024\n\t" \
        "global_load_dwordx4 %2, %[h], off offset:2048\n\t" \
        "global_load_dwordx4 %3, %[h], off offset:3072" \
        : "=&v"(Bv[0]), "=&v"(Bv[1]), "=&v"(Bv[2]), "=&v"(Bv[3]) \
        : [h]"v"(PH) : "memory"); \
    asm volatile( \
        "global_load_dwordx4 %0, %[l], off\n\t" \
        "global_load_dwordx4 %1, %[l], off offset:1024\n\t" \
        "global_load_dwordx4 %2, %[l], off offset:2048\n\t" \
        "global_load_dwordx4 %3, %[l], off offset:3072" \
        : "=&v"(Bv[4]), "=&v"(Bv[5]), "=&v"(Bv[6]), "=&v"(Bv[7]) \
        : [l]"v"(PL) : "memory"); \
    } while (0)

#define WAITVM(N) do { \
        asm volatile("s_waitcnt vmcnt(" #N ")" ::: "memory"); \
        __builtin_amdgcn_sched_barrier(0); \
    } while (0)

__global__ __launch_bounds__(NTHR, 1) void gru_persist(
    const unsigned short* __restrict__ xhi,
    const unsigned short* __restrict__ xlo,
    const unsigned short* __restrict__ Whi,
    const unsigned short* __restrict__ Wlo,
    const float* __restrict__ bias,
    unsigned short* hhi0, unsigned short* hlo0,
    unsigned short* hhi1, unsigned short* hlo1,
    float* __restrict__ out,
    float* __restrict__ hlast,
    unsigned* bar)
{
    extern __shared__ char smem[];
    float* Cp = (float*)smem;                   // 128 tiles x CPS f32

    const int tid = threadIdx.x;
    const int wg  = blockIdx.x;

    const int lane = tid & 63;
    const int kw   = tid >> 6;                  // wave 0..7 = K-split
    const int l15  = lane & 15, quad = lane >> 4;
    const int cpw  = lane * 4;                  // unpadded (max 255 < CPS=260)

    // weight roots (tile-packed, cacheable): x-side kc = kw*2+ks, h-side kc = 16+kw*4+ks
    const unsigned short* wxh = Whi + ((size_t)(wg * 48 + kw * 2) * 4) * 512 + lane * 8;
    const unsigned short* wxl = Wlo + ((size_t)(wg * 48 + kw * 2) * 4) * 512 + lane * 8;
    const unsigned short* whh = Whi + ((size_t)(wg * 48 + 16 + kw * 4) * 4) * 512 + lane * 8;
    const unsigned short* whl = Wlo + ((size_t)(wg * 48 + 16 + kw * 4) * 4) * 512 + lane * 8;

    // epilogue: thread -> (batch b, 2 cols)
    const int b   = tid >> 3, j2 = tid & 7, lc0 = 2 * j2;
    const int mt_e = b >> 4, rt = b & 15;
    const int tb0  = 64 * (rt >> 2) + (rt & 3);
    const int c0   = wg * 16 + lc0;
    float bZ[2], bR[2], bE[2];
    bZ[0] = bias[c0];            bZ[1] = bias[c0 + 1];
    bR[0] = bias[H_ + c0];       bR[1] = bias[H_ + c0 + 1];
    bE[0] = bias[2 * H_ + c0];   bE[1] = bias[2 * H_ + c0 + 1];
    // h store idx (fragment-major)
    const int hidx = (((c0 >> 5) * 4 + mt_e) * 4 + ((c0 >> 3) & 3)) * 128 + rt * 8 + (c0 & 7);

    float hcur0 = 0.f, hcur1 = 0.f;             // persistent h state in regs

    floatx4 acc[16];
    #pragma unroll
    for (int i = 0; i < 16; ++i) acc[i] = (floatx4){0.f, 0.f, 0.f, 0.f};

    // prologue: x-side contribution for t=0
    x_gemm(acc, xhi, xlo, wxh, wxl,
           ((size_t)l15 * S_ + 0) * F_ + kw * 64 + quad * 8);

    #pragma unroll 1
    for (int t = 0; t < S_; ++t) {
        const unsigned short* hih = (t & 1) ? hhi1 : hhi0;
        const unsigned short* hil = (t & 1) ? hlo1 : hlo0;
        unsigned short* hoh = (t & 1) ? hhi0 : hhi1;
        unsigned short* hol = (t & 1) ? hlo0 : hlo1;

        // ---- h-phase: depth-2 pipeline, counted vmcnt (r10 ladder) ----
        const unsigned short* hb = hih + (size_t)kw * 8192 + lane * 8;
        const unsigned short* lb = hil + (size_t)kw * 8192 + lane * 8;
        short8 A0[8], A1[8], Bv[8];

        LOADH2(A0, hb, lb);                                   // ks0 A
        LOADW2(Bv, whh, whl);                                 // ks0 B
        LOADH2(A1, hb + 2048, lb + 2048);                     // ks1 A
        WAITVM(8);  mfma_block(acc, A0, Bv);                  // ks0
        LOADW2(Bv, whh + 2048, whl + 2048);                   // ks1 B
        LOADH2(A0, hb + 4096, lb + 4096);                     // ks2 A
        WAITVM(8);  mfma_block(acc, A1, Bv);                  // ks1
        LOADW2(Bv, whh + 4096, whl + 4096);                   // ks2 B
        LOADH2(A1, hb + 6144, lb + 6144);                     // ks3 A
        WAITVM(8);  mfma_block(acc, A0, Bv);                  // ks2
        LOADW2(Bv, whh + 6144, whl + 6144);                   // ks3 B
        WAITVM(0);  mfma_block(acc, A1, Bv);                  // ks3

        // ---- LDS reduction scratch ----
        #pragma unroll
        for (int mt = 0; mt < 4; ++mt)
            #pragma unroll
            for (int ct = 0; ct < 4; ++ct)
                *(floatx4*)&Cp[((kw * 4 + mt) * 4 + ct) * CPS + cpw] = acc[mt * 4 + ct];
        __syncthreads();

        // ---- epilogue: all 512 threads, 2 cols each; h stores ONLY ----
        float hn0, hn1;
        {
            unsigned short his0, his1, los0, los1;
            #pragma unroll
            for (int u = 0; u < 2; ++u) {
                const int lc = lc0 + u;
                const int ct = lc >> 2;
                const int off0 = tb0 + 16 * (lc & 3);
                float s0 = 0.f, s1 = 0.f, s2 = 0.f, s3 = 0.f;
                #pragma unroll
                for (int k2 = 0; k2 < 8; ++k2) {
                    const int tb = ((k2 * 4 + mt_e) * 4 + ct) * CPS + off0;
                    s0 += Cp[tb];      s1 += Cp[tb + 4];
                    s2 += Cp[tb + 8];  s3 += Cp[tb + 12];
                }
                float z   = 1.f / (1.f + __expf(-(s0 + bZ[u])));
                float rr  = 1.f / (1.f + __expf(-(s1 + bR[u])));
                float eta = tanh_fast(s2 + bE[u] + rr * tanh_fast(s3));
                float hc  = u ? hcur1 : hcur0;
                float v   = z * hc + (1.f - z) * eta;
                if (u) { hcur1 = v; hn1 = v; split2(v, his1, los1); }
                else   { hcur0 = v; hn0 = v; split2(v, his0, los0); }
            }
            unsigned hp = (unsigned)his0 | ((unsigned)his1 << 16);
            unsigned lp = (unsigned)los0 | ((unsigned)los1 << 16);
            asm volatile("global_store_dword %0, %1, off sc0 sc1"
                         :: "v"(&hoh[hidx]), "v"(hp) : "memory");
            asm volatile("global_store_dword %0, %1, off sc0 sc1"
                         :: "v"(&hol[hidx]), "v"(lp) : "memory");
        }

        if (t + 1 < S_) {
            // drain ONLY the 2 h stores, then arrive
            asm volatile("s_waitcnt vmcnt(0)" ::: "memory");
            __syncthreads();
            if (tid == 0)
                __hip_atomic_fetch_add(&bar[(wg & 7) * 32], 1u,
                                       __ATOMIC_RELAXED, __HIP_MEMORY_SCOPE_AGENT);

            // out store: no cross-WG consumer -> after arrive, off critical path
            {
                floatx2 ov = { hn0, hn1 };
                asm volatile("global_store_dwordx2 %0, %1, off sc0 sc1"
                             :: "v"(&out[((size_t)b * S_ + t) * H_ + c0]), "v"(ov)
                             : "memory");
            }

            // x-side GEMM for t+1 in the barrier shadow (acc reused, zeroed)
            #pragma unroll
            for (int i = 0; i < 16; ++i) acc[i] = (floatx4){0.f, 0.f, 0.f, 0.f};
            x_gemm(acc, xhi, xlo, wxh, wxl,
                   ((size_t)l15 * S_ + (t + 1)) * F_ + kw * 64 + quad * 8);

            // distributed-counter poll: 8 lines, one round trip per poll
            if (tid == 0) {
                const unsigned target = (unsigned)(t + 1) * NWG;
                for (;;) {
                    unsigned cc0, cc1, cc2, cc3, cc4, cc5, cc6, cc7;
                    asm volatile(
                        "global_load_dword %0, %[a0], off sc0 sc1\n\t"
                        "global_load_dword %1, %[a1], off sc0 sc1\n\t"
                        "global_load_dword %2, %[a2], off sc0 sc1\n\t"
                        "global_load_dword %3, %[a3], off sc0 sc1\n\t"
                        "global_load_dword %4, %[a4], off sc0 sc1\n\t"
                        "global_load_dword %5, %[a5], off sc0 sc1\n\t"
                        "global_load_dword %6, %[a6], off sc0 sc1\n\t"
                        "global_load_dword %7, %[a7], off sc0 sc1\n\t"
                        "s_waitcnt vmcnt(0)"
                        : "=&v"(cc0), "=&v"(cc1), "=&v"(cc2), "=&v"(cc3),
                          "=&v"(cc4), "=&v"(cc5), "=&v"(cc6), "=&v"(cc7)
                        : [a0]"v"(bar),       [a1]"v"(bar + 32),
                          [a2]"v"(bar + 64),  [a3]"v"(bar + 96),
                          [a4]"v"(bar + 128), [a5]"v"(bar + 160),
                          [a6]"v"(bar + 192), [a7]"v"(bar + 224)
                        : "memory");
                    if (cc0 + cc1 + cc2 + cc3 + cc4 + cc5 + cc6 + cc7 >= target) break;
                    __builtin_amdgcn_s_sleep(1);
                }
            }
            __syncthreads();
        } else {
            // last step: out + hlast, no barrier needed
            floatx2 ov = { hn0, hn1 };
            asm volatile("global_store_dwordx2 %0, %1, off sc0 sc1"
                         :: "v"(&out[((size_t)b * S_ + t) * H_ + c0]), "v"(ov)
                         : "memory");
            asm volatile("global_store_dwordx2 %0, %1, off sc0 sc1"
                         :: "v"(&hlast[b * H_ + c0]), "v"(ov) : "memory");
        }
    }
}

extern "C" void kernel_launch(void* const* d_in, const int* in_sizes, int n_in,
                              void* d_out, int out_size, void* d_ws, size_t ws_size,
                              hipStream_t stream) {
    const float* x    = (const float*)d_in[0];   // [B,S,F]
    const float* Wih  = (const float*)d_in[1];   // [F,3H]
    const float* Whh  = (const float*)d_in[2];   // [H,3H]
    const float* bias = (const float*)d_in[3];   // [3H]
    float* out = (float*)d_out;                  // [B,S,H] ++ [B,H]

    char* ws = (char*)d_ws;
    unsigned short* Whi = (unsigned short*)ws; ws += (size_t)NG * KTOT * 2;
    unsigned short* Wlo = (unsigned short*)ws; ws += (size_t)NG * KTOT * 2;
    unsigned short* xhi = (unsigned short*)ws; ws += (size_t)B_ * S_ * F_ * 2;
    unsigned short* xlo = (unsigned short*)ws; ws += (size_t)B_ * S_ * F_ * 2;
    unsigned short* hhi0 = (unsigned short*)ws; ws += (size_t)B_ * H_ * 2;
    unsigned short* hlo0 = (unsigned short*)ws; ws += (size_t)B_ * H_ * 2;
    unsigned short* hhi1 = (unsigned short*)ws; ws += (size_t)B_ * H_ * 2;
    unsigned short* hlo1 = (unsigned short*)ws; ws += (size_t)B_ * H_ * 2;
    unsigned* bar = (unsigned*)ws;             ws += 1024;

    hipMemsetAsync(hhi0, 0, (size_t)B_ * H_ * 2, stream);
    hipMemsetAsync(hlo0, 0, (size_t)B_ * H_ * 2, stream);
    hipMemsetAsync(bar,  0, 1024, stream);

    pack_w2<<<(NG * KTOT) / 256, 256, 0, stream>>>(Wih, Whh, Whi, Wlo);
    pack_x<<<(B_ * S_ * F_) / 256, 256, 0, stream>>>(x, xhi, xlo);

    float* hlast = out + (size_t)B_ * S_ * H_;
    void* args[] = { &xhi, &xlo, &Whi, &Wlo, &bias,
                     &hhi0, &hlo0, &hhi1, &hlo1, &out, &hlast, &bar };
    hipLaunchCooperativeKernel((void*)gru_persist, dim3(NWG), dim3(NTHR),
                               args, SMEM_BYTES, stream);
}